// Round 2
// baseline (500.067 us; speedup 1.0000x reference)
//
#include <hip/hip_runtime.h>
#include <hip/hip_fp16.h>
#include <math.h>

// GAT layer: N=100000, E=1600000, F=64, H=4 (Dh=16).
// Pipeline: fused {kq GEMM (fp16 out) | in-degree hist} -> scan ->
// fused score+scatter (fp16 gathers, stores exp(e_h) as 4xf32 + src stream) ->
// CSR gather-aggregate (f32 h gathers, packed-f32 math, 4-deep unroll) ->
// in-place out GEMM.
//
// Weight storage is raw f32 exp(e_h): the segment-max in the reference cancels
// algebraically in a = exp(e-m)/sum(exp(e-m)); e ~ N(0,16) so |e| < 40 and
// f32 exp never overflows/underflows. This removes the per-record decode
// (5 cvt + 8 mul, redundant across all 64 lanes) that dominated aggregate's
// VALU time, and removes the group-max shuffles + second expf from scatter.

#define FDIM 64
#define NHEADS 4

typedef float f32x2 __attribute__((ext_vector_type(2)));

// ---- K1: multi-role kernel: [0,KQB) kq | rest hist ----
__global__ __launch_bounds__(256) void fused_pre_kernel(
    const float* __restrict__ h, const float* __restrict__ Wk,
    const float* __restrict__ Wq, __half* __restrict__ k16,
    __half* __restrict__ q16, const int* __restrict__ dst,
    int* __restrict__ counts, int N, int E, int KQB)
{
    __shared__ float sWk[FDIM * FDIM];
    __shared__ float sWq[FDIM * FDIM];
    int bid = blockIdx.x;
    if (bid < KQB) {
        // --- kq role: k = h@Wk, q = h@Wq; thread = 2 rows x 16 cols x 2 mats ---
        for (int i = threadIdx.x; i < FDIM * FDIM; i += 256) {
            sWk[i] = Wk[i];
            sWq[i] = Wq[i];
        }
        __syncthreads();
        int cg = threadIdx.x & 3;
        int rg = threadIdx.x >> 2;
        long base = (long)bid * 128 + rg * 2;
        const float4* sWk4 = (const float4*)sWk;
        const float4* sWq4 = (const float4*)sWq;
        const float4* h4 = (const float4*)h;
        float acck[2][16], accq[2][16];
#pragma unroll
        for (int i = 0; i < 2; ++i)
#pragma unroll
            for (int c = 0; c < 16; ++c) { acck[i][c] = 0.f; accq[i][c] = 0.f; }

        for (int fs = 0; fs < FDIM; fs += 4) {
            float4 hv[2];
#pragma unroll
            for (int i = 0; i < 2; ++i) {
                long r = base + i; if (r >= N) r = N - 1;
                hv[i] = h4[r * 16 + (fs >> 2)];
            }
#pragma unroll
            for (int fi = 0; fi < 4; ++fi) {
                int f = fs + fi;
                float4 wk0 = sWk4[f * 16 + cg * 4 + 0];
                float4 wk1 = sWk4[f * 16 + cg * 4 + 1];
                float4 wk2 = sWk4[f * 16 + cg * 4 + 2];
                float4 wk3 = sWk4[f * 16 + cg * 4 + 3];
                float4 wq0 = sWq4[f * 16 + cg * 4 + 0];
                float4 wq1 = sWq4[f * 16 + cg * 4 + 1];
                float4 wq2 = sWq4[f * 16 + cg * 4 + 2];
                float4 wq3 = sWq4[f * 16 + cg * 4 + 3];
#pragma unroll
                for (int i = 0; i < 2; ++i) {
                    float hvf = (&hv[i].x)[fi];
                    acck[i][0]  = fmaf(hvf, wk0.x, acck[i][0]);
                    acck[i][1]  = fmaf(hvf, wk0.y, acck[i][1]);
                    acck[i][2]  = fmaf(hvf, wk0.z, acck[i][2]);
                    acck[i][3]  = fmaf(hvf, wk0.w, acck[i][3]);
                    acck[i][4]  = fmaf(hvf, wk1.x, acck[i][4]);
                    acck[i][5]  = fmaf(hvf, wk1.y, acck[i][5]);
                    acck[i][6]  = fmaf(hvf, wk1.z, acck[i][6]);
                    acck[i][7]  = fmaf(hvf, wk1.w, acck[i][7]);
                    acck[i][8]  = fmaf(hvf, wk2.x, acck[i][8]);
                    acck[i][9]  = fmaf(hvf, wk2.y, acck[i][9]);
                    acck[i][10] = fmaf(hvf, wk2.z, acck[i][10]);
                    acck[i][11] = fmaf(hvf, wk2.w, acck[i][11]);
                    acck[i][12] = fmaf(hvf, wk3.x, acck[i][12]);
                    acck[i][13] = fmaf(hvf, wk3.y, acck[i][13]);
                    acck[i][14] = fmaf(hvf, wk3.z, acck[i][14]);
                    acck[i][15] = fmaf(hvf, wk3.w, acck[i][15]);
                    accq[i][0]  = fmaf(hvf, wq0.x, accq[i][0]);
                    accq[i][1]  = fmaf(hvf, wq0.y, accq[i][1]);
                    accq[i][2]  = fmaf(hvf, wq0.z, accq[i][2]);
                    accq[i][3]  = fmaf(hvf, wq0.w, accq[i][3]);
                    accq[i][4]  = fmaf(hvf, wq1.x, accq[i][4]);
                    accq[i][5]  = fmaf(hvf, wq1.y, accq[i][5]);
                    accq[i][6]  = fmaf(hvf, wq1.z, accq[i][6]);
                    accq[i][7]  = fmaf(hvf, wq1.w, accq[i][7]);
                    accq[i][8]  = fmaf(hvf, wq2.x, accq[i][8]);
                    accq[i][9]  = fmaf(hvf, wq2.y, accq[i][9]);
                    accq[i][10] = fmaf(hvf, wq2.z, accq[i][10]);
                    accq[i][11] = fmaf(hvf, wq2.w, accq[i][11]);
                    accq[i][12] = fmaf(hvf, wq3.x, accq[i][12]);
                    accq[i][13] = fmaf(hvf, wq3.y, accq[i][13]);
                    accq[i][14] = fmaf(hvf, wq3.z, accq[i][14]);
                    accq[i][15] = fmaf(hvf, wq3.w, accq[i][15]);
                }
            }
        }
#pragma unroll
        for (int i = 0; i < 2; ++i) {
            long r = base + i;
            if (r >= N) continue;
            __half2 hk[8], hq[8];
#pragma unroll
            for (int c = 0; c < 8; ++c) {
                hk[c] = __floats2half2_rn(acck[i][2 * c], acck[i][2 * c + 1]);
                hq[c] = __floats2half2_rn(accq[i][2 * c], accq[i][2 * c + 1]);
            }
            float4* kout = (float4*)(k16 + (size_t)r * FDIM + cg * 16);
            float4* qout = (float4*)(q16 + (size_t)r * FDIM + cg * 16);
            kout[0] = ((float4*)hk)[0]; kout[1] = ((float4*)hk)[1];
            qout[0] = ((float4*)hq)[0]; qout[1] = ((float4*)hq)[1];
        }
    } else {
        // --- hist role: in-degree histogram ---
        int e = (bid - KQB) * 256 + threadIdx.x;
        if (e < E) atomicAdd(&counts[dst[e]], 1);
    }
}

// K2a: per-1024-chunk exclusive scan of counts -> rowptr, block totals -> bsum.
__global__ __launch_bounds__(256) void scan1_kernel(
    const int* __restrict__ counts, int* __restrict__ rowptr,
    int* __restrict__ bsum, int N)
{
    __shared__ int sd[256];
    int base = blockIdx.x * 1024;
    int t = threadIdx.x;
    int c[4];
    int s = 0;
#pragma unroll
    for (int i = 0; i < 4; ++i) {
        int idx = base + t * 4 + i;
        c[i] = (idx < N) ? counts[idx] : 0;
        s += c[i];
    }
    sd[t] = s;
    __syncthreads();
    for (int off = 1; off < 256; off <<= 1) {
        int v = (t >= off) ? sd[t - off] : 0;
        __syncthreads();
        sd[t] += v;
        __syncthreads();
    }
    int ex = sd[t] - s;
#pragma unroll
    for (int i = 0; i < 4; ++i) {
        int idx = base + t * 4 + i;
        if (idx < N) rowptr[idx] = ex;
        ex += c[i];
    }
    if (t == 255) bsum[blockIdx.x] = sd[255];
}

// K2b: single-block exclusive scan of bsum (NBLK <= 256).
__global__ __launch_bounds__(256) void scan2_kernel(int* __restrict__ bsum, int NBLK)
{
    __shared__ int sd[256];
    int t = threadIdx.x;
    int v = (t < NBLK) ? bsum[t] : 0;
    sd[t] = v;
    __syncthreads();
    for (int off = 1; off < 256; off <<= 1) {
        int u = (t >= off) ? sd[t - off] : 0;
        __syncthreads();
        sd[t] += u;
        __syncthreads();
    }
    if (t < NBLK) bsum[t] = sd[t] - v;
}

// K2c: add chunk offsets.
__global__ __launch_bounds__(256) void scan3_kernel(
    int* __restrict__ rowptr, const int* __restrict__ bsum, int N)
{
    int i = blockIdx.x * 256 + threadIdx.x;
    if (i < N) rowptr[i] += bsum[i >> 10];
}

// K3: fused score + scatter, 2 edges/thread. 4-lane group = one edge (lane hh
// = head). Per edge: gather fp16 k[src]/q[dst], dot over 16 dims, slot p from
// leader atomic broadcast via shfl, each lane stores its own f32 exp(e_h) at
// warr[4p+hh]; leader stores src at srcs[p]. No group-max needed (f32 range).
__global__ __launch_bounds__(256) void score_scatter_kernel(
    const int* __restrict__ src, const int* __restrict__ dst,
    int* __restrict__ rowptr, const __half* __restrict__ k16,
    const __half* __restrict__ q16, float* __restrict__ warr,
    int* __restrict__ srcs, int E)
{
    int t = blockIdx.x * 256 + threadIdx.x;
    int hh = t & 3;
    int Ehalf = (E + 1) >> 1;
    int eA = t >> 2;
    if (eA >= Ehalf) return;
    int eB = eA + Ehalf;
    bool hasB = (eB < E);
    int lane = threadIdx.x & 63;
    int base = lane & ~3;

    int sA = src[eA], dA = dst[eA];
    int sB = 0, dB = 0;
    if (hasB) { sB = src[eB]; dB = dst[eB]; }

    int pA = 0, pB = 0;
    if (hh == 0) {
        pA = atomicAdd(&rowptr[dA], 1);
        if (hasB) pB = atomicAdd(&rowptr[dB], 1);
    }
    pA = __shfl(pA, base, 64);
    pB = __shfl(pB, base, 64);

    // Issue all gathers up front for MLP.
    const float4* krA = (const float4*)(k16 + (size_t)sA * FDIM + hh * 16);
    const float4* qrA = (const float4*)(q16 + (size_t)dA * FDIM + hh * 16);
    float4 kA0 = krA[0], kA1 = krA[1];
    float4 qA0 = qrA[0], qA1 = qrA[1];
    float4 kB0, kB1, qB0, qB1;
    if (hasB) {
        const float4* krB = (const float4*)(k16 + (size_t)sB * FDIM + hh * 16);
        const float4* qrB = (const float4*)(q16 + (size_t)dB * FDIM + hh * 16);
        kB0 = krB[0]; kB1 = krB[1];
        qB0 = qrB[0]; qB1 = qrB[1];
    }

    // ---- edge A ----
    {
        float4 kv[2] = { kA0, kA1 }, qv[2] = { qA0, qA1 };
        const __half2* kh = (const __half2*)kv;
        const __half2* qh = (const __half2*)qv;
        float acc = 0.f;
#pragma unroll
        for (int j = 0; j < 8; ++j) {
            float2 kf = __half22float2(kh[j]);
            float2 qf = __half22float2(qh[j]);
            acc = fmaf(kf.x, qf.x, acc);
            acc = fmaf(kf.y, qf.y, acc);
        }
        float wA = expf(acc);
        warr[(size_t)pA * 4 + hh] = wA;
        if (hh == 0) srcs[pA] = sA;
    }
    // ---- edge B ---- (hasB uniform within the 4-lane group)
    if (hasB) {
        float4 kv[2] = { kB0, kB1 }, qv[2] = { qB0, qB1 };
        const __half2* kh = (const __half2*)kv;
        const __half2* qh = (const __half2*)qv;
        float acc = 0.f;
#pragma unroll
        for (int j = 0; j < 8; ++j) {
            float2 kf = __half22float2(kh[j]);
            float2 qf = __half22float2(qh[j]);
            acc = fmaf(kf.x, qf.x, acc);
            acc = fmaf(kf.y, qf.y, acc);
        }
        float wB = expf(acc);
        warr[(size_t)pB * 4 + hh] = wB;
        if (hh == 0) srcs[pB] = sB;
    }
}

// K4: gather aggregation over CSR rows. One wave per node; lane = feature.
// Weights pre-exponentiated f32 (warr) + src stream (srcs). f32 h gather.
// Packed-f32 accumulate (v_pk_fma_f32 / v_pk_add_f32) over head pairs,
// 4-record unroll to pipeline the srcs->gather dependent chain.
__device__ __forceinline__ void agg_one(
    float4 wv, float hv,
    f32x2& a01, f32x2& a23, f32x2& z01, f32x2& z23)
{
    f32x2 hb;  hb.x = hv;    hb.y = hv;
    f32x2 wlo; wlo.x = wv.x; wlo.y = wv.y;
    f32x2 whi; whi.x = wv.z; whi.y = wv.w;
    a01 = __builtin_elementwise_fma(wlo, hb, a01);
    a23 = __builtin_elementwise_fma(whi, hb, a23);
    z01 += wlo;
    z23 += whi;
}

__global__ __launch_bounds__(256) void aggregate_kernel(
    const int* __restrict__ rowend, const float4* __restrict__ warr,
    const int* __restrict__ srcs, const float* __restrict__ h,
    float* __restrict__ hn, int N)
{
    int lane = threadIdx.x & 63;
    int n = blockIdx.x * 4 + (threadIdx.x >> 6);
    if (n >= N) return;
    int end   = rowend[n];
    int start = (n == 0) ? 0 : rowend[n - 1];
    f32x2 a01 = {0.f, 0.f}, a23 = {0.f, 0.f};
    f32x2 z01 = {0.f, 0.f}, z23 = {0.f, 0.f};
    const float* hl = h + lane;

    int i = start;
    for (; i + 3 < end; i += 4) {
        float4 w0 = warr[i], w1 = warr[i + 1], w2 = warr[i + 2], w3 = warr[i + 3];
        int s0 = srcs[i], s1 = srcs[i + 1], s2 = srcs[i + 2], s3 = srcs[i + 3];
        float hv0 = hl[(size_t)s0 * FDIM];
        float hv1 = hl[(size_t)s1 * FDIM];
        float hv2 = hl[(size_t)s2 * FDIM];
        float hv3 = hl[(size_t)s3 * FDIM];
        agg_one(w0, hv0, a01, a23, z01, z23);
        agg_one(w1, hv1, a01, a23, z01, z23);
        agg_one(w2, hv2, a01, a23, z01, z23);
        agg_one(w3, hv3, a01, a23, z01, z23);
    }
    for (; i < end; ++i) {
        float4 w0 = warr[i];
        int s0 = srcs[i];
        float hv0 = hl[(size_t)s0 * FDIM];
        agg_one(w0, hv0, a01, a23, z01, z23);
    }

    float* outr = hn + (size_t)n * (NHEADS * FDIM);
    if (end > start) {
        outr[lane]             = a01.x / z01.x;
        outr[FDIM + lane]      = a01.y / z01.y;
        outr[2 * FDIM + lane]  = a23.x / z23.x;
        outr[3 * FDIM + lane]  = a23.y / z23.y;
    } else {
        outr[lane] = 0.f;
        outr[FDIM + lane] = 0.f;
        outr[2 * FDIM + lane] = 0.f;
        outr[3 * FDIM + lane] = 0.f;
    }
}

// K5: out = hn @ W + b, IN PLACE (hn == out == d_out). Thread = 4 rows x 16 cols.
// In-place safe: the 4 threads sharing a row-group are consecutive lanes of one
// wave, so all row reads complete before any store (lockstep).
__global__ __launch_bounds__(256) void out_kernel(
    const float* hn, const float* __restrict__ W,
    const float* __restrict__ b, float* out, int R)
{
    __shared__ float sW[FDIM * FDIM];
    __shared__ float sb[FDIM];
    for (int i = threadIdx.x; i < FDIM * FDIM; i += 256) sW[i] = W[i];
    if (threadIdx.x < FDIM) sb[threadIdx.x] = b[threadIdx.x];
    __syncthreads();
    int cg = threadIdx.x & 3;
    int rg = threadIdx.x >> 2;
    long base = (long)blockIdx.x * 256 + rg * 4;
    const float4* sW4 = (const float4*)sW;
    const float4* hn4 = (const float4*)hn;
    float acc[4][16];
#pragma unroll
    for (int i = 0; i < 4; ++i)
#pragma unroll
        for (int c = 0; c < 16; ++c) acc[i][c] = sb[cg * 16 + c];

    for (int fs = 0; fs < FDIM; fs += 4) {
        float4 hv[4];
#pragma unroll
        for (int i = 0; i < 4; ++i) {
            long r = base + i; if (r >= R) r = R - 1;
            hv[i] = hn4[r * 16 + (fs >> 2)];
        }
#pragma unroll
        for (int fi = 0; fi < 4; ++fi) {
            int f = fs + fi;
            float4 w0 = sW4[f * 16 + cg * 4 + 0];
            float4 w1 = sW4[f * 16 + cg * 4 + 1];
            float4 w2 = sW4[f * 16 + cg * 4 + 2];
            float4 w3 = sW4[f * 16 + cg * 4 + 3];
#pragma unroll
            for (int i = 0; i < 4; ++i) {
                float hvf = (&hv[i].x)[fi];
                acc[i][0]  = fmaf(hvf, w0.x, acc[i][0]);
                acc[i][1]  = fmaf(hvf, w0.y, acc[i][1]);
                acc[i][2]  = fmaf(hvf, w0.z, acc[i][2]);
                acc[i][3]  = fmaf(hvf, w0.w, acc[i][3]);
                acc[i][4]  = fmaf(hvf, w1.x, acc[i][4]);
                acc[i][5]  = fmaf(hvf, w1.y, acc[i][5]);
                acc[i][6]  = fmaf(hvf, w1.z, acc[i][6]);
                acc[i][7]  = fmaf(hvf, w1.w, acc[i][7]);
                acc[i][8]  = fmaf(hvf, w2.x, acc[i][8]);
                acc[i][9]  = fmaf(hvf, w2.y, acc[i][9]);
                acc[i][10] = fmaf(hvf, w2.z, acc[i][10]);
                acc[i][11] = fmaf(hvf, w2.w, acc[i][11]);
                acc[i][12] = fmaf(hvf, w3.x, acc[i][12]);
                acc[i][13] = fmaf(hvf, w3.y, acc[i][13]);
                acc[i][14] = fmaf(hvf, w3.z, acc[i][14]);
                acc[i][15] = fmaf(hvf, w3.w, acc[i][15]);
            }
        }
    }
#pragma unroll
    for (int i = 0; i < 4; ++i) {
        long r = base + i;
        if (r >= R) continue;
        float4* o = (float4*)(out + (size_t)r * FDIM + cg * 16);
#pragma unroll
        for (int c4 = 0; c4 < 4; ++c4)
            o[c4] = make_float4(acc[i][c4*4], acc[i][c4*4+1], acc[i][c4*4+2], acc[i][c4*4+3]);
    }
}

extern "C" void kernel_launch(void* const* d_in, const int* in_sizes, int n_in,
                              void* d_out, int out_size, void* d_ws, size_t ws_size,
                              hipStream_t stream) {
    const float* h   = (const float*)d_in[0];
    const int*   src = (const int*)d_in[1];
    const int*   dst = (const int*)d_in[2];
    const float* Wk  = (const float*)d_in[3];
    const float* Wq  = (const float*)d_in[4];
    const float* W   = (const float*)d_in[5];
    const float* b   = (const float*)d_in[6];
    float* out = (float*)d_out;

    const int N = in_sizes[0] / FDIM;   // 100000
    const int E = in_sizes[1];          // 1600000

    // Workspace: k16[N*64 h], q16[N*64 h], warr[E float4], srcs[E int],
    //            counts[N], rowptr[N], bsum[256].  (~58.4 MB)
    __half* k16 = (__half*)d_ws;
    __half* q16 = k16 + (size_t)N * FDIM;
    float* warr = (float*)(q16 + (size_t)N * FDIM);
    int* srcs   = (int*)(warr + (size_t)E * 4);
    int* counts = srcs + E;
    int* rowptr = counts + N;
    int* bsum   = rowptr + N;

    const int NBLK = (N + 1023) / 1024;            // 98
    const int KQB  = (N + 127) / 128;              // 782
    const int HIB  = (E + 255) / 256;              // 6250
    const int Ehalf = (E + 1) >> 1;

    hipMemsetAsync(counts, 0, (size_t)N * sizeof(int), stream);

    fused_pre_kernel<<<KQB + HIB, 256, 0, stream>>>(
        h, Wk, Wq, k16, q16, dst, counts, N, E, KQB);
    scan1_kernel<<<NBLK, 256, 0, stream>>>(counts, rowptr, bsum, N);
    scan2_kernel<<<1, 256, 0, stream>>>(bsum, NBLK);
    scan3_kernel<<<(N + 255) / 256, 256, 0, stream>>>(rowptr, bsum, N);
    score_scatter_kernel<<<(Ehalf * NHEADS + 255) / 256, 256, 0, stream>>>(
        src, dst, rowptr, k16, q16, warr, srcs, E);
    aggregate_kernel<<<(N + 3) / 4, 256, 0, stream>>>(
        rowptr, (const float4*)warr, srcs, h, out, N);
    out_kernel<<<(N * NHEADS + 255) / 256, 256, 0, stream>>>(out, W, b, out, N * NHEADS);
}